// Round 6
// baseline (133.860 us; speedup 1.0000x reference)
//
#include <hip/hip_runtime.h>
#include <hip/hip_cooperative_groups.h>

namespace cg = cooperative_groups;

#define IMG_H 512
#define IMG_W 512
#define PLANE (IMG_H * IMG_W)
#define NBATCH 64
#define NBINS 256
#define TSTRIP 16                               // rows per wave-strip
#define WAVES_PER_BLOCK 4
#define STRIPS_PER_IMG (IMG_H / TSTRIP)         // 32
#define BLOCKS_PER_IMG (STRIPS_PER_IMG / WAVES_PER_BLOCK)  // 8
#define NBLOCKS (BLOCKS_PER_IMG * NBATCH)       // 512

#define GRAY(rr, gg, bb) (0.2989f * (rr) + 0.587f * (gg) + 0.114f * (bb))

// One wave walks a 16-row x 512-wide strip with a 3-row register ring (R4
// structure: snake walk + XCD swizzle, no staging barrier). After grid.sync(),
// 64 blocks (one per image, co-located with that image's partials on the same
// XCD) reduce + L2-normalize.
__global__ __launch_bounds__(256) void lbp_fused_kernel(const float* __restrict__ x,
                                                        float* __restrict__ ws,
                                                        float* __restrict__ out) {
    __shared__ unsigned int lh[NBINS];
    const int tid = threadIdx.x;
    lh[tid] = 0u;                                // 256 threads == 256 bins
    __syncthreads();

    // XCD swizzle: XCD = blockIdx.x % 8 (round-robin). Image = sid>>3 groups
    // 8 blocks (one image) onto one XCD.
    const int lin = blockIdx.x;                  // 0..511
    const int sid = (lin & 7) * (NBLOCKS / 8) + (lin >> 3);
    const int b   = sid >> 3;                    // image 0..63
    const int bg  = sid & 7;                     // strip-group 0..7

    const int wav   = tid >> 6;                  // 0..3
    const int lane  = tid & 63;
    const int strip = bg * WAVES_PER_BLOCK + wav;   // 0..31
    const int y0    = strip * TSTRIP;

    const float* rP = x + (size_t)b * 3 * PLANE;
    const float* gP = rP + PLANE;
    const float* bP = rP + 2 * PLANE;
    const int    cx = 8 * lane;                  // lane's first column

    // arr[0]=left edge (col cx-1), arr[1..8]=cols cx..cx+7, arr[9]=right edge (col cx+8)
    float t_[10], m_[10], b_[10];

    #define LOADGRAY(arr, gy_)                                                     \
    do {                                                                           \
        int gy = (gy_);                                                            \
        gy = gy < 0 ? 0 : (gy > IMG_H - 1 ? IMG_H - 1 : gy);                       \
        size_t off = (size_t)gy * IMG_W + cx;                                      \
        float4 ra = *(const float4*)(rP + off), rb = *(const float4*)(rP + off + 4);\
        float4 ga = *(const float4*)(gP + off), gb = *(const float4*)(gP + off + 4);\
        float4 ba = *(const float4*)(bP + off), bb = *(const float4*)(bP + off + 4);\
        arr[1] = GRAY(ra.x, ga.x, ba.x); arr[2] = GRAY(ra.y, ga.y, ba.y);          \
        arr[3] = GRAY(ra.z, ga.z, ba.z); arr[4] = GRAY(ra.w, ga.w, ba.w);          \
        arr[5] = GRAY(rb.x, gb.x, bb.x); arr[6] = GRAY(rb.y, gb.y, bb.y);          \
        arr[7] = GRAY(rb.z, gb.z, bb.z); arr[8] = GRAY(rb.w, gb.w, bb.w);          \
        float lft = __shfl_up(arr[8], 1, 64);                                      \
        float rgt = __shfl_down(arr[1], 1, 64);                                    \
        arr[0] = (lane == 0)  ? arr[1] : lft;                                      \
        arr[9] = (lane == 63) ? arr[8] : rgt;                                      \
    } while (0)

    // OFFSETS = ((-1,-1),(-1,0),(-1,1),(0,1),(1,1),(1,0),(1,-1),(0,-1))
    #define COMPUTE8()                                                             \
    do {                                                                           \
        _Pragma("unroll")                                                          \
        for (int p = 0; p < 8; ++p) {                                              \
            const float ctr = m_[p + 1];                                           \
            unsigned code = 0u;                                                    \
            code |= (t_[p    ] >= ctr) ? 1u   : 0u;                                \
            code |= (t_[p + 1] >= ctr) ? 2u   : 0u;                                \
            code |= (t_[p + 2] >= ctr) ? 4u   : 0u;                                \
            code |= (m_[p + 2] >= ctr) ? 8u   : 0u;                                \
            code |= (b_[p + 2] >= ctr) ? 16u  : 0u;                                \
            code |= (b_[p + 1] >= ctr) ? 32u  : 0u;                                \
            code |= (b_[p    ] >= ctr) ? 64u  : 0u;                                \
            code |= (m_[p    ] >= ctr) ? 128u : 0u;                                \
            atomicAdd(&lh[code], 1u);                                              \
        }                                                                          \
    } while (0)

    if ((strip & 1) == 0) {
        // walk top -> bottom
        LOADGRAY(t_, y0 - 1);
        LOADGRAY(m_, y0);
        #pragma unroll 4
        for (int i = 0; i < TSTRIP; ++i) {
            LOADGRAY(b_, y0 + 1 + i);
            COMPUTE8();
            #pragma unroll
            for (int k = 0; k < 10; ++k) { t_[k] = m_[k]; m_[k] = b_[k]; }
        }
    } else {
        // walk bottom -> top
        LOADGRAY(b_, y0 + TSTRIP);
        LOADGRAY(m_, y0 + TSTRIP - 1);
        #pragma unroll 4
        for (int i = 0; i < TSTRIP; ++i) {
            LOADGRAY(t_, y0 + TSTRIP - 2 - i);
            COMPUTE8();
            #pragma unroll
            for (int k = 0; k < 10; ++k) { b_[k] = m_[k]; m_[k] = t_[k]; }
        }
    }
    #undef LOADGRAY
    #undef COMPUTE8

    __syncthreads();
    // one partial histogram per block
    ws[((size_t)b * BLOCKS_PER_IMG + bg) * NBINS + tid] = (float)lh[tid];

    __threadfence();
    cg::this_grid().sync();

    // ---- fused finalize: block sid==8*fb reduces image fb (same-XCD ws reads) ----
    if (bg == 0) {
        const int fb = b;
        float s = 0.0f;
        #pragma unroll
        for (int k = 0; k < BLOCKS_PER_IMG; ++k)
            s += ws[((size_t)fb * BLOCKS_PER_IMG + k) * NBINS + tid];
        float ssq = s * s;
        #pragma unroll
        for (int o = 32; o > 0; o >>= 1) ssq += __shfl_down(ssq, o, 64);
        __shared__ float wsum[4];
        if ((tid & 63) == 0) wsum[tid >> 6] = ssq;
        __syncthreads();
        float tot = wsum[0] + wsum[1] + wsum[2] + wsum[3];
        out[fb * NBINS + tid] = s / (sqrtf(tot) + 1e-6f);
    }
}

extern "C" void kernel_launch(void* const* d_in, const int* in_sizes, int n_in,
                              void* d_out, int out_size, void* d_ws, size_t ws_size,
                              hipStream_t stream) {
    const float* x = (const float*)d_in[0];
    float* out = (float*)d_out;
    float* ws  = (float*)d_ws;   // 64 * 8 * 256 floats = 512 KB partial histograms

    void* args[] = { (void*)&x, (void*)&ws, (void*)&out };
    hipLaunchCooperativeKernel((void*)lbp_fused_kernel, dim3(NBLOCKS), dim3(256),
                               args, 0, stream);
}

// Round 7
// 40.596 us; speedup vs baseline: 3.2974x; 3.2974x over previous
//
#include <hip/hip_runtime.h>

#define IMG_H 512
#define IMG_W 512
#define PLANE (IMG_H * IMG_W)
#define NBATCH 64
#define NBINS 256
#define TSTRIP 8                                // rows per wave-strip
#define WAVES_PER_BLOCK 4
#define STRIPS_PER_IMG (IMG_H / TSTRIP)         // 64
#define BLOCKS_PER_IMG (STRIPS_PER_IMG / WAVES_PER_BLOCK)  // 16
#define NBLOCKS (BLOCKS_PER_IMG * NBATCH)       // 1024 -> 4 blocks/CU, 16 waves/CU

#define GRAY(rr, gg, bb) (0.2989f * (rr) + 0.587f * (gg) + 0.114f * (bb))

// One wave walks an 8-row x 512-wide strip with a 3-row register ring.
// Snake walk + XCD swizzle for L2 reuse of boundary rows. No staging barrier.
__global__ __launch_bounds__(256) void lbp_strip_kernel(const float* __restrict__ x,
                                                        float* __restrict__ ws) {
    __shared__ unsigned int lh[NBINS];
    const int tid = threadIdx.x;
    lh[tid] = 0u;                                // 256 threads == 256 bins
    __syncthreads();

    // XCD swizzle: XCD = blockIdx.x % 8 (round-robin). sid groups 128
    // consecutive blocks (= 8 whole images) per XCD.
    const int lin = blockIdx.x;                  // 0..1023
    const int sid = (lin & 7) * (NBLOCKS / 8) + (lin >> 3);
    const int b   = sid >> 4;                    // image 0..63
    const int bg  = sid & 15;                    // strip-group 0..15

    const int wav   = tid >> 6;                  // 0..3
    const int lane  = tid & 63;
    const int strip = bg * WAVES_PER_BLOCK + wav;   // 0..63
    const int y0    = strip * TSTRIP;

    const float* rP = x + (size_t)b * 3 * PLANE;
    const float* gP = rP + PLANE;
    const float* bP = rP + 2 * PLANE;
    const int    cx = 8 * lane;                  // lane's first column

    // arr[0]=left edge (col cx-1), arr[1..8]=cols cx..cx+7, arr[9]=right edge (col cx+8)
    float t_[10], m_[10], b_[10];

    #define LOADGRAY(arr, gy_)                                                     \
    do {                                                                           \
        int gy = (gy_);                                                            \
        gy = gy < 0 ? 0 : (gy > IMG_H - 1 ? IMG_H - 1 : gy);                       \
        size_t off = (size_t)gy * IMG_W + cx;                                      \
        float4 ra = *(const float4*)(rP + off), rb = *(const float4*)(rP + off + 4);\
        float4 ga = *(const float4*)(gP + off), gb = *(const float4*)(gP + off + 4);\
        float4 ba = *(const float4*)(bP + off), bb = *(const float4*)(bP + off + 4);\
        arr[1] = GRAY(ra.x, ga.x, ba.x); arr[2] = GRAY(ra.y, ga.y, ba.y);          \
        arr[3] = GRAY(ra.z, ga.z, ba.z); arr[4] = GRAY(ra.w, ga.w, ba.w);          \
        arr[5] = GRAY(rb.x, gb.x, bb.x); arr[6] = GRAY(rb.y, gb.y, bb.y);          \
        arr[7] = GRAY(rb.z, gb.z, bb.z); arr[8] = GRAY(rb.w, gb.w, bb.w);          \
        float lft = __shfl_up(arr[8], 1, 64);                                      \
        float rgt = __shfl_down(arr[1], 1, 64);                                    \
        arr[0] = (lane == 0)  ? arr[1] : lft;                                      \
        arr[9] = (lane == 63) ? arr[8] : rgt;                                      \
    } while (0)

    // OFFSETS = ((-1,-1),(-1,0),(-1,1),(0,1),(1,1),(1,0),(1,-1),(0,-1))
    #define COMPUTE8()                                                             \
    do {                                                                           \
        _Pragma("unroll")                                                          \
        for (int p = 0; p < 8; ++p) {                                              \
            const float ctr = m_[p + 1];                                           \
            unsigned code = 0u;                                                    \
            code |= (t_[p    ] >= ctr) ? 1u   : 0u;                                \
            code |= (t_[p + 1] >= ctr) ? 2u   : 0u;                                \
            code |= (t_[p + 2] >= ctr) ? 4u   : 0u;                                \
            code |= (m_[p + 2] >= ctr) ? 8u   : 0u;                                \
            code |= (b_[p + 2] >= ctr) ? 16u  : 0u;                                \
            code |= (b_[p + 1] >= ctr) ? 32u  : 0u;                                \
            code |= (b_[p    ] >= ctr) ? 64u  : 0u;                                \
            code |= (m_[p    ] >= ctr) ? 128u : 0u;                                \
            atomicAdd(&lh[code], 1u);                                              \
        }                                                                          \
    } while (0)

    if ((strip & 1) == 0) {
        // walk top -> bottom
        LOADGRAY(t_, y0 - 1);
        LOADGRAY(m_, y0);
        #pragma unroll
        for (int i = 0; i < TSTRIP; ++i) {
            LOADGRAY(b_, y0 + 1 + i);
            COMPUTE8();
            #pragma unroll
            for (int k = 0; k < 10; ++k) { t_[k] = m_[k]; m_[k] = b_[k]; }
        }
    } else {
        // walk bottom -> top
        LOADGRAY(b_, y0 + TSTRIP);
        LOADGRAY(m_, y0 + TSTRIP - 1);
        #pragma unroll
        for (int i = 0; i < TSTRIP; ++i) {
            LOADGRAY(t_, y0 + TSTRIP - 2 - i);
            COMPUTE8();
            #pragma unroll
            for (int k = 0; k < 10; ++k) { b_[k] = m_[k]; m_[k] = t_[k]; }
        }
    }
    #undef LOADGRAY
    #undef COMPUTE8

    __syncthreads();
    // one partial histogram per block, no global atomics
    ws[((size_t)b * BLOCKS_PER_IMG + bg) * NBINS + tid] = (float)lh[tid];
}

// Sum the 16 partials per image, L2-normalize, write output.
__global__ __launch_bounds__(256) void finalize_kernel(const float* __restrict__ ws,
                                                       float* __restrict__ out) {
    const int b = blockIdx.x;
    const int t = threadIdx.x;
    float s = 0.0f;
    #pragma unroll
    for (int k = 0; k < BLOCKS_PER_IMG; ++k)
        s += ws[((size_t)b * BLOCKS_PER_IMG + k) * NBINS + t];
    float ss = s * s;
    #pragma unroll
    for (int o = 32; o > 0; o >>= 1) ss += __shfl_down(ss, o, 64);
    __shared__ float wsum[4];
    if ((t & 63) == 0) wsum[t >> 6] = ss;
    __syncthreads();
    float tot = wsum[0] + wsum[1] + wsum[2] + wsum[3];
    out[b * NBINS + t] = s / (sqrtf(tot) + 1e-6f);
}

extern "C" void kernel_launch(void* const* d_in, const int* in_sizes, int n_in,
                              void* d_out, int out_size, void* d_ws, size_t ws_size,
                              hipStream_t stream) {
    const float* x = (const float*)d_in[0];
    float* out = (float*)d_out;
    float* ws  = (float*)d_ws;   // 64 * 16 * 256 floats = 1 MB partial histograms

    lbp_strip_kernel<<<NBLOCKS, 256, 0, stream>>>(x, ws);
    finalize_kernel<<<NBATCH, 256, 0, stream>>>(ws, out);
}

// Round 8
// 39.936 us; speedup vs baseline: 3.3519x; 1.0165x over previous
//
#include <hip/hip_runtime.h>

#define IMG_H 512
#define IMG_W 512
#define PLANE (IMG_H * IMG_W)
#define NBATCH 64
#define NBINS 256
#define TSTRIP 16                               // rows per wave-strip
#define WAVES_PER_BLOCK 4
#define STRIPS_PER_IMG (IMG_H / TSTRIP)         // 32
#define BLOCKS_PER_IMG (STRIPS_PER_IMG / WAVES_PER_BLOCK)  // 8
#define NBLOCKS (BLOCKS_PER_IMG * NBATCH)       // 512

#define GRAY(rr, gg, bb) (0.2989f * (rr) + 0.587f * (gg) + 0.114f * (bb))

// One wave walks a 16-row x 512-wide strip with a 3-row gray register ring and
// a 2-slot raw-load pipeline (loads issued ~2 rows ahead of use). Snake walk +
// XCD swizzle. No staging barrier, no LDS staging.
__global__ __launch_bounds__(256) void lbp_strip_kernel(const float* __restrict__ x,
                                                        float* __restrict__ ws) {
    __shared__ unsigned int lh[NBINS];
    const int tid = threadIdx.x;
    lh[tid] = 0u;                                // 256 threads == 256 bins
    __syncthreads();

    // XCD swizzle: XCD = blockIdx.x % 8 (round-robin). Image = sid>>3 groups
    // 8 blocks (one image) onto one XCD.
    const int lin = blockIdx.x;                  // 0..511
    const int sid = (lin & 7) * (NBLOCKS / 8) + (lin >> 3);
    const int b   = sid >> 3;                    // image 0..63
    const int bg  = sid & 7;                     // strip-group 0..7

    const int wav   = tid >> 6;                  // 0..3
    const int lane  = tid & 63;
    const int strip = bg * WAVES_PER_BLOCK + wav;   // 0..31
    const int y0    = strip * TSTRIP;

    const float* rP = x + (size_t)b * 3 * PLANE;
    const float* gP = rP + PLANE;
    const float* bP = rP + 2 * PLANE;
    const int    cx = 8 * lane;                  // lane's first column

    // Two named raw prefetch slots (no runtime indexing -> stays in VGPRs).
    float4 Ar0, Ar1, Ag0, Ag1, Ab0, Ab1;
    float4 Br0, Br1, Bg0, Bg1, Bb0, Bb1;

    // arr[0]=left edge (col cx-1), arr[1..8]=cols cx..cx+7, arr[9]=right edge
    float t_[10], m_[10], b_[10];

    // Issue the 6 vector loads for a row into slot s (no consumption here).
    #define ISSUE(s, gy_)                                                          \
    do {                                                                           \
        int gy = (gy_);                                                            \
        gy = gy < 0 ? 0 : (gy > IMG_H - 1 ? IMG_H - 1 : gy);                       \
        size_t off = (size_t)gy * IMG_W + cx;                                      \
        s##r0 = *(const float4*)(rP + off); s##r1 = *(const float4*)(rP + off + 4);\
        s##g0 = *(const float4*)(gP + off); s##g1 = *(const float4*)(gP + off + 4);\
        s##b0 = *(const float4*)(bP + off); s##b1 = *(const float4*)(bP + off + 4);\
    } while (0)

    // Convert slot s to gray row arr (this is where the vmcnt wait lands).
    #define GRAYF(arr, s)                                                          \
    do {                                                                           \
        arr[1] = GRAY(s##r0.x, s##g0.x, s##b0.x);                                  \
        arr[2] = GRAY(s##r0.y, s##g0.y, s##b0.y);                                  \
        arr[3] = GRAY(s##r0.z, s##g0.z, s##b0.z);                                  \
        arr[4] = GRAY(s##r0.w, s##g0.w, s##b0.w);                                  \
        arr[5] = GRAY(s##r1.x, s##g1.x, s##b1.x);                                  \
        arr[6] = GRAY(s##r1.y, s##g1.y, s##b1.y);                                  \
        arr[7] = GRAY(s##r1.z, s##g1.z, s##b1.z);                                  \
        arr[8] = GRAY(s##r1.w, s##g1.w, s##b1.w);                                  \
        float lft = __shfl_up(arr[8], 1, 64);                                      \
        float rgt = __shfl_down(arr[1], 1, 64);                                    \
        arr[0] = (lane == 0)  ? arr[1] : lft;                                      \
        arr[9] = (lane == 63) ? arr[8] : rgt;                                      \
    } while (0)

    // OFFSETS = ((-1,-1),(-1,0),(-1,1),(0,1),(1,1),(1,0),(1,-1),(0,-1))
    #define COMPUTE8()                                                             \
    do {                                                                           \
        _Pragma("unroll")                                                          \
        for (int p = 0; p < 8; ++p) {                                              \
            const float ctr = m_[p + 1];                                           \
            unsigned code = 0u;                                                    \
            code |= (t_[p    ] >= ctr) ? 1u   : 0u;                                \
            code |= (t_[p + 1] >= ctr) ? 2u   : 0u;                                \
            code |= (t_[p + 2] >= ctr) ? 4u   : 0u;                                \
            code |= (m_[p + 2] >= ctr) ? 8u   : 0u;                                \
            code |= (b_[p + 2] >= ctr) ? 16u  : 0u;                                \
            code |= (b_[p + 1] >= ctr) ? 32u  : 0u;                                \
            code |= (b_[p    ] >= ctr) ? 64u  : 0u;                                \
            code |= (m_[p    ] >= ctr) ? 128u : 0u;                                \
            atomicAdd(&lh[code], 1u);                                              \
        }                                                                          \
    } while (0)

    #define SHIFT_DN()                                                             \
    do { _Pragma("unroll")                                                         \
         for (int k = 0; k < 10; ++k) { t_[k] = m_[k]; m_[k] = b_[k]; } } while (0)
    #define SHIFT_UP()                                                             \
    do { _Pragma("unroll")                                                         \
         for (int k = 0; k < 10; ++k) { b_[k] = m_[k]; m_[k] = t_[k]; } } while (0)

    if ((strip & 1) == 0) {
        // walk top -> bottom: rows y0-1 .. y0+16
        ISSUE(A, y0 - 1);
        ISSUE(B, y0);
        GRAYF(t_, A);
        ISSUE(A, y0 + 1);
        GRAYF(m_, B);
        ISSUE(B, y0 + 2);
        #pragma unroll
        for (int i = 0; i < TSTRIP; i += 2) {
            GRAYF(b_, A);                            // row y0+1+i
            if (i + 3 <= TSTRIP) ISSUE(A, y0 + i + 3);
            COMPUTE8();                              // center y0+i
            SHIFT_DN();
            GRAYF(b_, B);                            // row y0+2+i
            if (i + 4 <= TSTRIP) ISSUE(B, y0 + i + 4);
            COMPUTE8();                              // center y0+i+1
            SHIFT_DN();
        }
    } else {
        // walk bottom -> top: rows y0+16 .. y0-1
        ISSUE(A, y0 + TSTRIP);
        ISSUE(B, y0 + TSTRIP - 1);
        GRAYF(b_, A);
        ISSUE(A, y0 + TSTRIP - 2);
        GRAYF(m_, B);
        ISSUE(B, y0 + TSTRIP - 3);
        #pragma unroll
        for (int i = 0; i < TSTRIP; i += 2) {
            GRAYF(t_, A);                            // row y0+T-2-i
            if (i + 3 <= TSTRIP) ISSUE(A, y0 + TSTRIP - 4 - i);
            COMPUTE8();                              // center y0+T-1-i
            SHIFT_UP();
            GRAYF(t_, B);                            // row y0+T-3-i
            if (i + 4 <= TSTRIP) ISSUE(B, y0 + TSTRIP - 5 - i);
            COMPUTE8();                              // center y0+T-2-i
            SHIFT_UP();
        }
    }
    #undef ISSUE
    #undef GRAYF
    #undef COMPUTE8
    #undef SHIFT_DN
    #undef SHIFT_UP

    __syncthreads();
    // one partial histogram per block, no global atomics
    ws[((size_t)b * BLOCKS_PER_IMG + bg) * NBINS + tid] = (float)lh[tid];
}

// Sum the 8 partials per image, L2-normalize, write output.
__global__ __launch_bounds__(256) void finalize_kernel(const float* __restrict__ ws,
                                                       float* __restrict__ out) {
    const int b = blockIdx.x;
    const int t = threadIdx.x;
    float s = 0.0f;
    #pragma unroll
    for (int k = 0; k < BLOCKS_PER_IMG; ++k)
        s += ws[((size_t)b * BLOCKS_PER_IMG + k) * NBINS + t];
    float ss = s * s;
    #pragma unroll
    for (int o = 32; o > 0; o >>= 1) ss += __shfl_down(ss, o, 64);
    __shared__ float wsum[4];
    if ((t & 63) == 0) wsum[t >> 6] = ss;
    __syncthreads();
    float tot = wsum[0] + wsum[1] + wsum[2] + wsum[3];
    out[b * NBINS + t] = s / (sqrtf(tot) + 1e-6f);
}

extern "C" void kernel_launch(void* const* d_in, const int* in_sizes, int n_in,
                              void* d_out, int out_size, void* d_ws, size_t ws_size,
                              hipStream_t stream) {
    const float* x = (const float*)d_in[0];
    float* out = (float*)d_out;
    float* ws  = (float*)d_ws;   // 64 * 8 * 256 floats = 512 KB partial histograms

    lbp_strip_kernel<<<NBLOCKS, 256, 0, stream>>>(x, ws);
    finalize_kernel<<<NBATCH, 256, 0, stream>>>(ws, out);
}

// Round 9
// 38.999 us; speedup vs baseline: 3.4324x; 1.0240x over previous
//
#include <hip/hip_runtime.h>

#define IMG_H 512
#define IMG_W 512
#define PLANE (IMG_H * IMG_W)
#define NBATCH 64
#define NBINS 256
#define TSTRIP 32                               // rows per wave-strip
#define WAVES_PER_BLOCK 4
#define STRIPS_PER_IMG (IMG_H / TSTRIP)         // 16
#define BLOCKS_PER_IMG (STRIPS_PER_IMG / WAVES_PER_BLOCK)  // 4
#define NBLOCKS (BLOCKS_PER_IMG * NBATCH)       // 256 -> exactly 1 block/CU

#define GRAY(rr, gg, bb) (0.2989f * (rr) + 0.587f * (gg) + 0.114f * (bb))

// One wave walks a 32-row x 512-wide strip with a 3-row register ring.
// Snake walk + XCD swizzle. Halo = 34/32 rows (+6.25% fetch).
__global__ __launch_bounds__(256) void lbp_strip_kernel(const float* __restrict__ x,
                                                        float* __restrict__ ws) {
    __shared__ unsigned int lh[NBINS];
    const int tid = threadIdx.x;
    lh[tid] = 0u;                                // 256 threads == 256 bins
    __syncthreads();

    // XCD swizzle: XCD = blockIdx.x % 8 (round-robin). Groups each image's
    // 4 blocks onto one XCD.
    const int lin = blockIdx.x;                  // 0..255
    const int sid = (lin & 7) * (NBLOCKS / 8) + (lin >> 3);
    const int b   = sid >> 2;                    // image 0..63
    const int bg  = sid & 3;                     // strip-group 0..3

    const int wav   = tid >> 6;                  // 0..3
    const int lane  = tid & 63;
    const int strip = bg * WAVES_PER_BLOCK + wav;   // 0..15
    const int y0    = strip * TSTRIP;

    const float* rP = x + (size_t)b * 3 * PLANE;
    const float* gP = rP + PLANE;
    const float* bP = rP + 2 * PLANE;
    const int    cx = 8 * lane;                  // lane's first column

    // arr[0]=left edge (col cx-1), arr[1..8]=cols cx..cx+7, arr[9]=right edge (col cx+8)
    float t_[10], m_[10], b_[10];

    #define LOADGRAY(arr, gy_)                                                     \
    do {                                                                           \
        int gy = (gy_);                                                            \
        gy = gy < 0 ? 0 : (gy > IMG_H - 1 ? IMG_H - 1 : gy);                       \
        size_t off = (size_t)gy * IMG_W + cx;                                      \
        float4 ra = *(const float4*)(rP + off), rb = *(const float4*)(rP + off + 4);\
        float4 ga = *(const float4*)(gP + off), gb = *(const float4*)(gP + off + 4);\
        float4 ba = *(const float4*)(bP + off), bb = *(const float4*)(bP + off + 4);\
        arr[1] = GRAY(ra.x, ga.x, ba.x); arr[2] = GRAY(ra.y, ga.y, ba.y);          \
        arr[3] = GRAY(ra.z, ga.z, ba.z); arr[4] = GRAY(ra.w, ga.w, ba.w);          \
        arr[5] = GRAY(rb.x, gb.x, bb.x); arr[6] = GRAY(rb.y, gb.y, bb.y);          \
        arr[7] = GRAY(rb.z, gb.z, bb.z); arr[8] = GRAY(rb.w, gb.w, bb.w);          \
        float lft = __shfl_up(arr[8], 1, 64);                                      \
        float rgt = __shfl_down(arr[1], 1, 64);                                    \
        arr[0] = (lane == 0)  ? arr[1] : lft;                                      \
        arr[9] = (lane == 63) ? arr[8] : rgt;                                      \
    } while (0)

    // OFFSETS = ((-1,-1),(-1,0),(-1,1),(0,1),(1,1),(1,0),(1,-1),(0,-1))
    #define COMPUTE8()                                                             \
    do {                                                                           \
        _Pragma("unroll")                                                          \
        for (int p = 0; p < 8; ++p) {                                              \
            const float ctr = m_[p + 1];                                           \
            unsigned code = 0u;                                                    \
            code |= (t_[p    ] >= ctr) ? 1u   : 0u;                                \
            code |= (t_[p + 1] >= ctr) ? 2u   : 0u;                                \
            code |= (t_[p + 2] >= ctr) ? 4u   : 0u;                                \
            code |= (m_[p + 2] >= ctr) ? 8u   : 0u;                                \
            code |= (b_[p + 2] >= ctr) ? 16u  : 0u;                                \
            code |= (b_[p + 1] >= ctr) ? 32u  : 0u;                                \
            code |= (b_[p    ] >= ctr) ? 64u  : 0u;                                \
            code |= (m_[p    ] >= ctr) ? 128u : 0u;                                \
            atomicAdd(&lh[code], 1u);                                              \
        }                                                                          \
    } while (0)

    if ((strip & 1) == 0) {
        // walk top -> bottom
        LOADGRAY(t_, y0 - 1);
        LOADGRAY(m_, y0);
        #pragma unroll 4
        for (int i = 0; i < TSTRIP; ++i) {
            LOADGRAY(b_, y0 + 1 + i);
            COMPUTE8();
            #pragma unroll
            for (int k = 0; k < 10; ++k) { t_[k] = m_[k]; m_[k] = b_[k]; }
        }
    } else {
        // walk bottom -> top
        LOADGRAY(b_, y0 + TSTRIP);
        LOADGRAY(m_, y0 + TSTRIP - 1);
        #pragma unroll 4
        for (int i = 0; i < TSTRIP; ++i) {
            LOADGRAY(t_, y0 + TSTRIP - 2 - i);
            COMPUTE8();
            #pragma unroll
            for (int k = 0; k < 10; ++k) { b_[k] = m_[k]; m_[k] = t_[k]; }
        }
    }
    #undef LOADGRAY
    #undef COMPUTE8

    __syncthreads();
    // one partial histogram per block, no global atomics
    ws[((size_t)b * BLOCKS_PER_IMG + bg) * NBINS + tid] = (float)lh[tid];
}

// Sum the 4 partials per image, L2-normalize, write output.
__global__ __launch_bounds__(256) void finalize_kernel(const float* __restrict__ ws,
                                                       float* __restrict__ out) {
    const int b = blockIdx.x;
    const int t = threadIdx.x;
    float s = 0.0f;
    #pragma unroll
    for (int k = 0; k < BLOCKS_PER_IMG; ++k)
        s += ws[((size_t)b * BLOCKS_PER_IMG + k) * NBINS + t];
    float ss = s * s;
    #pragma unroll
    for (int o = 32; o > 0; o >>= 1) ss += __shfl_down(ss, o, 64);
    __shared__ float wsum[4];
    if ((t & 63) == 0) wsum[t >> 6] = ss;
    __syncthreads();
    float tot = wsum[0] + wsum[1] + wsum[2] + wsum[3];
    out[b * NBINS + t] = s / (sqrtf(tot) + 1e-6f);
}

extern "C" void kernel_launch(void* const* d_in, const int* in_sizes, int n_in,
                              void* d_out, int out_size, void* d_ws, size_t ws_size,
                              hipStream_t stream) {
    const float* x = (const float*)d_in[0];
    float* out = (float*)d_out;
    float* ws  = (float*)d_ws;   // 64 * 4 * 256 floats = 256 KB partial histograms

    lbp_strip_kernel<<<NBLOCKS, 256, 0, stream>>>(x, ws);
    finalize_kernel<<<NBATCH, 256, 0, stream>>>(ws, out);
}

// Round 10
// 37.491 us; speedup vs baseline: 3.5705x; 1.0402x over previous
//
#include <hip/hip_runtime.h>

#define IMG_H 512
#define IMG_W 512
#define PLANE (IMG_H * IMG_W)
#define NBATCH 64
#define NBINS 256
#define TSTRIP 16                               // rows per strip
#define HALF_W 256                              // columns per wave (half strip)
#define WPB 4                                   // waves per block
#define BLOCKS_PER_IMG 16                       // 64 wave-tasks / 4
#define NBLOCKS (BLOCKS_PER_IMG * NBATCH)       // 1024 -> 4 blocks/CU, 16 waves/CU

#define GRAY(rr, gg, bb) (0.2989f * (rr) + 0.587f * (gg) + 0.114f * (bb))

// One wave walks a 16-row x 256-col half-strip, 4 px/lane, 3-row register ring.
// Same total fetched bytes as the full-width version, but 2x waves/CU for
// latency hiding. Seam column (255/256) via 3 scalar loads on the edge lane.
// LBP code built MSB-first with v_cmp + v_addc (2 VALU per neighbor).
__global__ __launch_bounds__(256) void lbp_strip_kernel(const float* __restrict__ x,
                                                        float* __restrict__ ws) {
    __shared__ unsigned int lh[NBINS];
    const int tid = threadIdx.x;
    lh[tid] = 0u;                                // 256 threads == 256 bins
    __syncthreads();

    // XCD swizzle: XCD = blockIdx.x % 8; sid groups 128 blocks (8 images) per XCD.
    const int lin = blockIdx.x;                  // 0..1023
    const int sid = (lin & 7) * (NBLOCKS / 8) + (lin >> 3);
    const int b   = sid >> 4;                    // image 0..63
    const int bg  = sid & 15;                    // block-group 0..15

    const int wav   = tid >> 6;                  // 0..3
    const int lane  = tid & 63;
    const int strip = bg * 2 + (wav >> 1);       // 0..31 (16-row strip)
    const int half  = wav & 1;                   // 0 = cols 0..255, 1 = 256..511
    const int y0    = strip * TSTRIP;

    const float* rP = x + (size_t)b * 3 * PLANE;
    const float* gP = rP + PLANE;
    const float* bP = rP + 2 * PLANE;
    const int    cx = half * HALF_W + 4 * lane;  // lane's first column

    // arr[0]=left neighbor (col cx-1), arr[1..4]=cols cx..cx+3, arr[5]=right (col cx+4)
    float t_[6], m_[6], b_[6];

    #define LOADGRAY(arr, gy_)                                                     \
    do {                                                                           \
        int gy = (gy_);                                                            \
        gy = gy < 0 ? 0 : (gy > IMG_H - 1 ? IMG_H - 1 : gy);                       \
        size_t off = (size_t)gy * IMG_W + cx;                                      \
        float4 ra = *(const float4*)(rP + off);                                    \
        float4 ga = *(const float4*)(gP + off);                                    \
        float4 ba = *(const float4*)(bP + off);                                    \
        arr[1] = GRAY(ra.x, ga.x, ba.x); arr[2] = GRAY(ra.y, ga.y, ba.y);          \
        arr[3] = GRAY(ra.z, ga.z, ba.z); arr[4] = GRAY(ra.w, ga.w, ba.w);          \
        arr[0] = __shfl_up(arr[4], 1, 64);                                         \
        arr[5] = __shfl_down(arr[1], 1, 64);                                       \
        if (lane == 0)                                                             \
            arr[0] = half ? GRAY(rP[off - 1], gP[off - 1], bP[off - 1]) : arr[1];  \
        if (lane == 63)                                                            \
            arr[5] = half ? arr[4] : GRAY(rP[off + 4], gP[off + 4], bP[off + 4]);  \
    } while (0)

    // code = 2*code + (nei >= ctr), vcc-carry form (2 VALU per neighbor)
    #define LBPBIT(nei)                                                            \
        asm volatile("v_cmp_ge_f32 vcc, %1, %2\n\t"                                \
                     "v_addc_co_u32 %0, vcc, %0, %0, vcc"                          \
                     : "+v"(code) : "v"(nei), "v"(ctr) : "vcc")

    // OFFSETS bits: 1:(-1,-1) 2:(-1,0) 4:(-1,1) 8:(0,1) 16:(1,1) 32:(1,0)
    //               64:(1,-1) 128:(0,-1).  MSB-first Horner order below.
    #define COMPUTE4()                                                             \
    do {                                                                           \
        _Pragma("unroll")                                                          \
        for (int p = 0; p < 4; ++p) {                                              \
            const float ctr = m_[p + 1];                                           \
            unsigned code = 0u;                                                    \
            LBPBIT(m_[p    ]);   /* 128 */                                         \
            LBPBIT(b_[p    ]);   /*  64 */                                         \
            LBPBIT(b_[p + 1]);   /*  32 */                                         \
            LBPBIT(b_[p + 2]);   /*  16 */                                         \
            LBPBIT(m_[p + 2]);   /*   8 */                                         \
            LBPBIT(t_[p + 2]);   /*   4 */                                         \
            LBPBIT(t_[p + 1]);   /*   2 */                                         \
            LBPBIT(t_[p    ]);   /*   1 */                                         \
            atomicAdd(&lh[code], 1u);                                              \
        }                                                                          \
    } while (0)

    if ((strip & 1) == 0) {
        // walk top -> bottom
        LOADGRAY(t_, y0 - 1);
        LOADGRAY(m_, y0);
        #pragma unroll
        for (int i = 0; i < TSTRIP; ++i) {
            LOADGRAY(b_, y0 + 1 + i);
            COMPUTE4();
            #pragma unroll
            for (int k = 0; k < 6; ++k) { t_[k] = m_[k]; m_[k] = b_[k]; }
        }
    } else {
        // walk bottom -> top
        LOADGRAY(b_, y0 + TSTRIP);
        LOADGRAY(m_, y0 + TSTRIP - 1);
        #pragma unroll
        for (int i = 0; i < TSTRIP; ++i) {
            LOADGRAY(t_, y0 + TSTRIP - 2 - i);
            COMPUTE4();
            #pragma unroll
            for (int k = 0; k < 6; ++k) { b_[k] = m_[k]; m_[k] = t_[k]; }
        }
    }
    #undef LOADGRAY
    #undef LBPBIT
    #undef COMPUTE4

    __syncthreads();
    // one partial histogram per block, no global atomics
    ws[((size_t)b * BLOCKS_PER_IMG + bg) * NBINS + tid] = (float)lh[tid];
}

// Sum the 16 partials per image, L2-normalize, write output.
__global__ __launch_bounds__(256) void finalize_kernel(const float* __restrict__ ws,
                                                       float* __restrict__ out) {
    const int b = blockIdx.x;
    const int t = threadIdx.x;
    float s = 0.0f;
    #pragma unroll
    for (int k = 0; k < BLOCKS_PER_IMG; ++k)
        s += ws[((size_t)b * BLOCKS_PER_IMG + k) * NBINS + t];
    float ss = s * s;
    #pragma unroll
    for (int o = 32; o > 0; o >>= 1) ss += __shfl_down(ss, o, 64);
    __shared__ float wsum[4];
    if ((t & 63) == 0) wsum[t >> 6] = ss;
    __syncthreads();
    float tot = wsum[0] + wsum[1] + wsum[2] + wsum[3];
    out[b * NBINS + t] = s / (sqrtf(tot) + 1e-6f);
}

extern "C" void kernel_launch(void* const* d_in, const int* in_sizes, int n_in,
                              void* d_out, int out_size, void* d_ws, size_t ws_size,
                              hipStream_t stream) {
    const float* x = (const float*)d_in[0];
    float* out = (float*)d_out;
    float* ws  = (float*)d_ws;   // 64 * 16 * 256 floats = 1 MB partial histograms

    lbp_strip_kernel<<<NBLOCKS, 256, 0, stream>>>(x, ws);
    finalize_kernel<<<NBATCH, 256, 0, stream>>>(ws, out);
}